// Round 1
// 122.455 us; speedup vs baseline: 1.1647x; 1.1647x over previous
//
#include <hip/hip_runtime.h>
#include <math.h>

// Elementwise: s = sigmoid(x); logits = log(s/(1-s)) + log(u/(1-u));
// w = sigmoid(logits / 0.5); mask = w > 0.5; weights = mask ? w : 0.
// Outputs concatenated: [weights (N*N fp32)] [mask as 0/1 fp32 (N*N)].
//
// Round 6: guard-banded fast path.
//   Mathematically log(sigmoid(x)/(1-sigmoid(x))) == x, so logits = x + c.
//   The fp32 roundtrip error of the reference chain is <= ~2e-7 * e^max(x,0)
//   (the 1-s cancellation amplifies for x>0): <= 6e-4 for x <= 8.
//   Therefore when |x+c| > TAU=2e-3 and x <= 8, the reference's mask
//   decision (w > 0.5) is provably sign(x+c) (the float-sigmoid decision
//   deadzone is only ~6e-8 wide), and the weight sigmoid(2(x+c)) computed
//   with v_exp_f32 + v_rcp_f32 is within ~1e-5 of the reference -- far
//   inside the 0.02 absmax threshold. Elements inside the band (~0.16% of
//   data) or with x > 8 (reference saturation quirk: s==1 -> r=0 ->
//   log(0)=-inf -> w=0) take the original bit-exact libm chain.
//   Do NOT widen the fast path past these guards: mask flips are 0.5-1.0
//   errors vs the 0.02 threshold.
//
// Memory policy (round 5, kept): loads CACHEABLE (input is 256 MiB == L3
// size), stores NONTEMPORAL (write-once streams must not thrash L2/L3).

typedef float f32x4 __attribute__((ext_vector_type(4)));

struct WM { float w; float m; };

// Exact reference chain -- bit-identical to numpy (absmax 0.0 in prior
// rounds). Used for guard-band and saturation-zone elements only.
__device__ WM bern_slow(float x, float c) {
    float s = 1.0f / (1.0f + expf(-x));
    float om = 1.0f - s;
    float r = (om == 0.0f) ? 0.0f : (s / om);   // divide_no_nan(s, 1-s)
    float l1 = logf(r);                          // log(0) -> -inf, matches np
    float logits = l1 + c;
    float t = logits * 2.0f;                     // logits / 0.5 (exact)
    float w = 1.0f / (1.0f + expf(-t));
    bool mk = w > 0.5f;                          // EPSILON = 0.5
    WM o;
    o.w = mk ? w : 0.0f;
    o.m = mk ? 1.0f : 0.0f;
    return o;
}

#define TAU  2e-3f   // > max roundtrip logit error (6e-4 at x=8), margin 3x
#define XCUT 8.0f    // above this the 1-s cancellation error exceeds TAU

__device__ __forceinline__ WM bern_elem(float x, float c) {
    float L = x + c;                             // logits, up to roundtrip err
    if (__builtin_expect((fabsf(L) < TAU) || (x > XCUT), 0))
        return bern_slow(x, c);
    // exp(-2L) = 2^(L * -2*log2(e)); v_exp_f32 + v_rcp_f32, ~1 ulp each.
    float e = __builtin_amdgcn_exp2f(L * -2.8853900817779268f);
    float w = __builtin_amdgcn_rcpf(1.0f + e);
    bool mk = L > 0.0f;                          // provably == (w_ref > 0.5)
    WM o;
    o.w = mk ? w : 0.0f;
    o.m = mk ? 1.0f : 0.0f;
    return o;
}

__device__ __forceinline__ void bern_vec4(f32x4 x, float c, f32x4& w, f32x4& m) {
    WM a = bern_elem(x.x, c);
    WM b = bern_elem(x.y, c);
    WM d = bern_elem(x.z, c);
    WM e = bern_elem(x.w, c);
    w.x = a.w; m.x = a.m;
    w.y = b.w; m.y = b.m;
    w.z = d.w; m.z = d.m;
    w.w = e.w; m.w = e.m;
}

__global__ void Bernoulli_22428319220264_kernel(const float* __restrict__ sim,
                                                const float* __restrict__ noise,
                                                float* __restrict__ weights,
                                                float* __restrict__ mask,
                                                size_t n4) {
    float u = noise[0];
    float ud = 1.0f - u;
    float r = (ud == 0.0f) ? 0.0f : (u / ud);   // divide_no_nan(u, 1-u)
    float c = logf(r);                           // logit of the noise scalar

    const f32x4* in4 = (const f32x4*)sim;
    f32x4* w4 = (f32x4*)weights;
    f32x4* m4 = (f32x4*)mask;

    size_t stride = (size_t)gridDim.x * blockDim.x;
    size_t i = (size_t)blockIdx.x * blockDim.x + threadIdx.x;
    size_t stride4 = 4 * stride;

    // 4x unrolled grid-stride: four independent cacheable 16B loads in
    // flight; stores are nontemporal (no L2/L3 allocation).
    size_t iend_hi = (n4 >= 3 * stride) ? (n4 - 3 * stride) : 0;
    for (; i < iend_hi; i += stride4) {
        f32x4 x0 = in4[i];
        f32x4 x1 = in4[i + stride];
        f32x4 x2 = in4[i + 2 * stride];
        f32x4 x3 = in4[i + 3 * stride];
        f32x4 w0, m0, w1, m1, w2, m2, w3, m3;
        bern_vec4(x0, c, w0, m0);
        bern_vec4(x1, c, w1, m1);
        bern_vec4(x2, c, w2, m2);
        bern_vec4(x3, c, w3, m3);
        __builtin_nontemporal_store(w0, w4 + i);
        __builtin_nontemporal_store(m0, m4 + i);
        __builtin_nontemporal_store(w1, w4 + i + stride);
        __builtin_nontemporal_store(m1, m4 + i + stride);
        __builtin_nontemporal_store(w2, w4 + i + 2 * stride);
        __builtin_nontemporal_store(m2, m4 + i + 2 * stride);
        __builtin_nontemporal_store(w3, w4 + i + 3 * stride);
        __builtin_nontemporal_store(m3, m4 + i + 3 * stride);
    }
    for (; i < n4; i += stride) {
        f32x4 x = in4[i];
        f32x4 w, m;
        bern_vec4(x, c, w, m);
        __builtin_nontemporal_store(w, w4 + i);
        __builtin_nontemporal_store(m, m4 + i);
    }
}

extern "C" void kernel_launch(void* const* d_in, const int* in_sizes, int n_in,
                              void* d_out, int out_size, void* d_ws, size_t ws_size,
                              hipStream_t stream) {
    const float* sim = (const float*)d_in[0];
    const float* noise = (const float*)d_in[1];
    size_t n = (size_t)in_sizes[0];          // N*N = 67108864
    float* weights = (float*)d_out;
    float* mask = (float*)d_out + n;

    size_t n4 = n / 4;                        // 16777216 f32x4
    int block = 256;
    int grid = 2048;                          // 524288 threads; 32 f32x4/thread
    Bernoulli_22428319220264_kernel<<<grid, block, 0, stream>>>(sim, noise, weights, mask, n4);
}